// Round 2
// baseline (522.055 us; speedup 1.0000x reference)
//
#include <hip/hip_runtime.h>
#include <math.h>

#define NB 4
#define C 96
#define C3 288
#define NH 8
#define CHD 12
#define HT 160
#define WD 160
#define HW 25600

typedef unsigned short u16;
typedef unsigned int   u32;

__device__ __forceinline__ float gelu_f(float x){
    return 0.5f * x * (1.0f + erff(x * 0.7071067811865475f));
}
__device__ __forceinline__ float sigmoid_f(float x){
    return 1.0f / (1.0f + expf(-x));
}
__device__ __forceinline__ u16 f2bf(float x){
    union { float f; u32 u; } v; v.f = x;
    u32 r = v.u + 0x7FFFu + ((v.u >> 16) & 1u);
    return (u16)(r >> 16);
}
__device__ __forceinline__ float bf2f(u16 s){
    union { u32 u; float f; } v; v.u = ((u32)s) << 16;
    return v.f;
}

// ---------------- K0: per-(b,c) spatial sums of raw x -----------------------
__global__ __launch_bounds__(256) void k0_xsum(const float* __restrict__ x,
                                               float* __restrict__ xsum){
    int bc = blockIdx.x;                       // 0..383
    const float4* p4 = (const float4*)(x + (size_t)bc * HW);
    float s = 0.f;
    for (int i = threadIdx.x; i < HW/4; i += 256){
        float4 v = p4[i];
        s += (v.x + v.y) + (v.z + v.w);
    }
    __shared__ float red[256];
    red[threadIdx.x] = s;
    __syncthreads();
    for (int off = 128; off > 0; off >>= 1){
        if (threadIdx.x < off) red[threadIdx.x] += red[threadIdx.x + off];
        __syncthreads();
    }
    if (threadIdx.x == 0) xsum[bc] = red[0];
}

// ---------------- K1: all tiny per-batch math --------------------------------
__global__ void k1_small(const float* __restrict__ spectral, const float* __restrict__ xsum,
                         const float* __restrict__ w_se1, const float* __restrict__ b_se1,
                         const float* __restrict__ w_se2, const float* __restrict__ b_se2,
                         const float* __restrict__ w_saw1, const float* __restrict__ b_saw1,
                         const float* __restrict__ w_saw2, const float* __restrict__ b_saw2,
                         const float* __restrict__ w_sgp, const float* __restrict__ b_sgp,
                         const float* __restrict__ w_qkv,
                         float* __restrict__ swg, float* __restrict__ esgg,
                         float* __restrict__ weff){
    __shared__ float spec[96];
    __shared__ float h1[192];
    __shared__ float sw[96];
    __shared__ float cm_s;
    __shared__ float g1[9][24];
    __shared__ float saw[8];
    __shared__ float redbuf[96];
    int t = threadIdx.x;
    for (int b = 0; b < NB; b++){
        if (t < 96) spec[t] = spectral[b*96 + t];
        __syncthreads();
        if (t < 192){
            float a = b_se1[t];
            for (int c = 0; c < 96; c++) a += spec[c] * w_se1[t*96 + c];
            h1[t] = gelu_f(a);
        }
        __syncthreads();
        if (t < 96){
            float a = b_se2[t];
            for (int j = 0; j < 192; j++) a += h1[j] * w_se2[t*192 + j];
            float s = sigmoid_f(a);
            sw[t] = s;
            swg[b*96 + t] = s;
            redbuf[t] = s * xsum[b*96 + t];
        }
        __syncthreads();
        if (t == 0){
            float cs = 0.f;
            for (int c = 0; c < 96; c++) cs += redbuf[c];
            cm_s = cs / (96.0f * (float)HW);
        }
        __syncthreads();
        float cm = cm_s;
        if (t < 9*24){
            int cat = t / 24, ch = t % 24;
            int ti = cat / 3, tj = cat % 3;
            float S = 0.f;
            for (int ki = 0; ki < 3; ki++){
                if (ti == 0 && ki == 0) continue;
                if (ti == 2 && ki == 2) continue;
                for (int kj = 0; kj < 3; kj++){
                    if (tj == 0 && kj == 0) continue;
                    if (tj == 2 && kj == 2) continue;
                    S += w_saw1[ch*9 + ki*3 + kj];
                }
            }
            g1[cat][ch] = gelu_f(cm * S + b_saw1[ch]);
        }
        __syncthreads();
        if (t < 8){
            float acc = 0.f;
            const float cnt[3] = {1.f, 158.f, 1.f};
            for (int cat = 0; cat < 9; cat++){
                float a = b_saw2[t];
                for (int ch = 0; ch < 24; ch++) a += w_saw2[t*24 + ch] * g1[cat][ch];
                acc += cnt[cat/3] * cnt[cat%3] * sigmoid_f(a);
            }
            saw[t] = acc / (float)HW;
        }
        __syncthreads();
        if (t < 96){
            float a = b_sgp[t];
            for (int j = 0; j < 96; j++) a += spec[j] * w_sgp[t*96 + j];
            esgg[b*96 + t] = a * saw[t/12];
        }
        for (int i = t; i < C3*96; i += 256){
            weff[(size_t)b*C3*96 + i] = w_qkv[i] * sw[i % 96];
        }
        __syncthreads();
    }
}

// ---------------- K2a: 1x1 conv (Weff @ x) for one batch, Y fp32 -------------
__global__ __launch_bounds__(256) void k2a_qkv(const float* __restrict__ x,
                                               const float* __restrict__ weff,
                                               float* __restrict__ Y, int b){
    int oc0 = blockIdx.y * 16;
    int px = blockIdx.x * 1024 + threadIdx.x * 4;
    __shared__ float wsm[16*96];
    for (int i = threadIdx.x; i < 16*96; i += 256)
        wsm[i] = weff[((size_t)b*C3 + oc0)*96 + i];
    __syncthreads();
    const float* xb = x + (size_t)b*C*HW + px;
    float acc[16][4];
    #pragma unroll
    for (int i = 0; i < 16; i++) acc[i][0]=acc[i][1]=acc[i][2]=acc[i][3]=0.f;
    for (int c = 0; c < 96; c++){
        float4 xv = *(const float4*)(xb + (size_t)c*HW);
        #pragma unroll
        for (int i = 0; i < 16; i++){
            float w = wsm[i*96 + c];
            acc[i][0] += w*xv.x; acc[i][1] += w*xv.y;
            acc[i][2] += w*xv.z; acc[i][3] += w*xv.w;
        }
    }
    float* Yb = Y + (size_t)oc0*HW + px;
    #pragma unroll
    for (int i = 0; i < 16; i++)
        *(float4*)(Yb + (size_t)i*HW) = make_float4(acc[i][0],acc[i][1],acc[i][2],acc[i][3]);
}

// ---------------- K2b: 3x3 depthwise on one batch, Y fp32 -> qkv bf16 --------
__global__ __launch_bounds__(256) void k2b_dw(const float* __restrict__ Y,
                                              const float* __restrict__ w_dw,
                                              u16* __restrict__ qkv, int b){
    int ch = blockIdx.y;
    int r0 = blockIdx.x * 8;
    __shared__ float tile[10*160];
    const float* Yc = Y + (size_t)ch*HW;
    for (int i = threadIdx.x; i < 1600; i += 256){
        int r = i / 160, col = i % 160;
        int gr = r0 + r - 1;
        tile[i] = (gr >= 0 && gr < HT) ? Yc[gr*WD + col] : 0.f;
    }
    float w[9];
    #pragma unroll
    for (int k = 0; k < 9; k++) w[k] = w_dw[ch*9 + k];
    __syncthreads();
    u16* qc = qkv + ((size_t)b*C3 + ch)*HW + r0*WD;
    for (int i = threadIdx.x; i < 640; i += 256){
        int r = i / 80, c2 = (i % 80) * 2;
        float a0 = 0.f, a1 = 0.f;
        #pragma unroll
        for (int ki = 0; ki < 3; ki++){
            const float* row = &tile[(r+ki)*160];
            #pragma unroll
            for (int kj = 0; kj < 3; kj++){
                float wv = w[ki*3+kj];
                int cc0 = c2 + kj - 1;
                int cc1 = cc0 + 1;
                if (cc0 >= 0 && cc0 < WD) a0 += wv * row[cc0];
                if (cc1 >= 0 && cc1 < WD) a1 += wv * row[cc1];
            }
        }
        u32 pk = (u32)f2bf(a0) | ((u32)f2bf(a1) << 16);
        *(u32*)(qc + r*WD + c2) = pk;
    }
}

// ---------------- K3: fc branch (flat-reshape einsum), fws bf16 (b,hw,108) ---
__global__ __launch_bounds__(256) void k3_fc(const u16* __restrict__ qkv,
                                             const float* __restrict__ w_fc,
                                             const float* __restrict__ b_fc,
                                             u16* __restrict__ fws){
    int b  = blockIdx.y;
    int n0 = blockIdx.x * 64;
    __shared__ u16 r[64*289];
    __shared__ float wfc[216];
    __shared__ float bfc[9];
    int t = threadIdx.x;
    if (t < 216) wfc[t] = w_fc[t];
    if (t < 9)   bfc[t] = b_fc[t];
    const u32* src = (const u32*)(qkv + (size_t)b*C3*HW + (size_t)n0*288);
    for (int i = t; i < 64*144; i += 256){
        u32 v = src[i];
        int row = (2*i) / 288, cc = (2*i) % 288;
        r[row*289 + cc]     = (u16)(v & 0xffffu);
        r[row*289 + cc + 1] = (u16)(v >> 16);
    }
    __syncthreads();
    for (int col = t; col < 768; col += 256){
        int nl = col / 12, d = col % 12;
        float rv[24];
        #pragma unroll
        for (int g = 0; g < 24; g++) rv[g] = bf2f(r[nl*289 + g*12 + d]);
        u16* dst = fws + ((size_t)b*HW + n0 + nl)*108 + d*9;
        #pragma unroll
        for (int o = 0; o < 9; o++){
            float a = bfc[o];
            #pragma unroll
            for (int g = 0; g < 24; g++) a += wfc[o*24 + g] * rv[g];
            dst[o] = f2bf(a);
        }
    }
}

// ---------------- K4: Gram partials G[c,d]=sum_n q_c k_d, plus norms ---------
__global__ __launch_bounds__(256) void k4_gram(const u16* __restrict__ qkv,
                                               float* __restrict__ gpart){
    int b = blockIdx.z;
    int h = blockIdx.y;
    int t = threadIdx.x;
    __shared__ float qs[12*268];
    __shared__ float ks[12*268];
    const u32* qu = (const u32*)(qkv + ((size_t)b*C3 + h*CHD)*HW + blockIdx.x*1024);
    const u32* ku = (const u32*)(qkv + ((size_t)b*C3 + C + h*CHD)*HW + blockIdx.x*1024);
    float acc = 0.f;
    for (int sc = 0; sc < 4; sc++){
        __syncthreads();
        for (int i = t; i < 12*128; i += 256){
            int rr = i / 128, pu = i % 128;
            u32 qv = qu[rr*(HW/2) + sc*128 + pu];
            u32 kv = ku[rr*(HW/2) + sc*128 + pu];
            qs[rr*268 + 2*pu]     = bf2f((u16)(qv & 0xffffu));
            qs[rr*268 + 2*pu + 1] = bf2f((u16)(qv >> 16));
            ks[rr*268 + 2*pu]     = bf2f((u16)(kv & 0xffffu));
            ks[rr*268 + 2*pu + 1] = bf2f((u16)(kv >> 16));
        }
        __syncthreads();
        if (t < 144){
            int c = t / 12, d = t % 12;
            const float* qq = &qs[c*268];
            const float* kk = &ks[d*268];
            float a = 0.f;
            for (int p = 0; p < 256; p += 4){
                float4 q4 = *(const float4*)(qq + p);
                float4 k4 = *(const float4*)(kk + p);
                a += q4.x*k4.x + q4.y*k4.y + q4.z*k4.z + q4.w*k4.w;
            }
            acc += a;
        } else if (t < 168){
            int c = (t - 144) % 12;
            const float* qq = (t < 156) ? &qs[c*268] : &ks[c*268];
            float a = 0.f;
            for (int p = 0; p < 256; p += 4){
                float4 q4 = *(const float4*)(qq + p);
                a += q4.x*q4.x + q4.y*q4.y + q4.z*q4.z + q4.w*q4.w;
            }
            acc += a;
        }
    }
    if (t < 168)
        gpart[(((size_t)b*NH + h)*25 + blockIdx.x)*168 + t] = acc;
}

// ---------------- K5: softmax + M[b] = W_proj @ blockdiag(attn) --------------
__global__ void k5_attn(const float* __restrict__ gpart, const float* __restrict__ esgg,
                        const float* __restrict__ temp, const float* __restrict__ w_proj,
                        float* __restrict__ Mm){
    int b = blockIdx.x;
    int t = threadIdx.x;
    __shared__ float G[NH][144];
    __shared__ float q2[NH][12], k2[NH][12];
    __shared__ float attn[NH][144];
    for (int i = t; i < NH*168; i += 256){
        int h = i / 168, e = i % 168;
        float a = 0.f;
        for (int ch = 0; ch < 25; ch++)
            a += gpart[(((size_t)b*NH + h)*25 + ch)*168 + e];
        if (e < 144)      G[h][e] = a;
        else if (e < 156) q2[h][e-144] = a;
        else              k2[h][e-156] = a;
    }
    __syncthreads();
    if (t < 96){
        int h = t / 12, c = t % 12;
        float rq  = 1.0f / fmaxf(sqrtf(q2[h][c]), 1e-12f);
        float tm  = temp[h];
        float egc = esgg[b*96 + h*12 + c];
        float lo[12];
        float mx = -1e30f;
        for (int d = 0; d < 12; d++){
            float rk = 1.0f / fmaxf(sqrtf(k2[h][d]), 1e-12f);
            float v = G[h][c*12 + d] * rq * rk * tm * (egc * esgg[b*96 + h*12 + d]);
            lo[d] = v;
            mx = fmaxf(mx, v);
        }
        float s = 0.f;
        for (int d = 0; d < 12; d++){ lo[d] = expf(lo[d] - mx); s += lo[d]; }
        float inv = 1.0f / s;
        for (int d = 0; d < 12; d++) attn[h][c*12 + d] = lo[d] * inv;
    }
    __syncthreads();
    for (int i = t; i < 96*96; i += 256){
        int co = i / 96, ci = i % 96;
        int h = ci / 12, d = ci % 12;
        float a = 0.f;
        #pragma unroll
        for (int c = 0; c < 12; c++)
            a += w_proj[co*96 + h*12 + c] * attn[h][c*12 + d];
        Mm[((size_t)b*96 + co)*96 + ci] = a;
    }
}

// ---------------- K6a: grouped 3x3 conv (out_conv) -> writes d_out -----------
__global__ __launch_bounds__(192) void k6a_dep(const u16* __restrict__ fws,
                                               const float* __restrict__ w_dep,
                                               const float* __restrict__ b_dep,
                                               float* __restrict__ out){
    int b  = blockIdx.z;
    int ti = blockIdx.y * 8, tj = blockIdx.x * 8;
    __shared__ u16 f[100*110];
    __shared__ float wl[96*81];
    int t = threadIdx.x;
    for (int i = t; i < 100*54; i += 192){
        int hp = i / 54, c2 = (i % 54) * 2;
        int gi = ti + hp/10 - 1, gj = tj + hp%10 - 1;
        u32 v = 0;
        if (gi >= 0 && gi < HT && gj >= 0 && gj < WD)
            v = *(const u32*)(fws + ((size_t)b*HW + gi*WD + gj)*108 + c2);
        f[hp*110 + c2]     = (u16)(v & 0xffffu);
        f[hp*110 + c2 + 1] = (u16)(v >> 16);
    }
    for (int i = t; i < 96*81; i += 192) wl[i] = w_dep[i];
    __syncthreads();
    int quad = t & 15;
    int gr   = t >> 4;                 // 0..11 (== group d)
    int pi0 = (quad >> 2) * 2, pj0 = (quad & 3) * 2;
    float acc[8][4];
    #pragma unroll
    for (int oo = 0; oo < 8; oo++){
        float bv = b_dep[gr*8 + oo];
        acc[oo][0]=acc[oo][1]=acc[oo][2]=acc[oo][3]=bv;
    }
    #pragma unroll
    for (int o = 0; o < 9; o++){
        float fr[4][4];
        #pragma unroll
        for (int ri = 0; ri < 4; ri++)
            #pragma unroll
            for (int rj = 0; rj < 4; rj++)
                fr[ri][rj] = bf2f(f[((pi0+ri)*10 + (pj0+rj))*110 + gr*9 + o]);
        #pragma unroll
        for (int oo = 0; oo < 8; oo++){
            const float* wp = &wl[(gr*8 + oo)*81 + o*9];
            #pragma unroll
            for (int ki = 0; ki < 3; ki++)
                #pragma unroll
                for (int kj = 0; kj < 3; kj++){
                    float w = wp[ki*3 + kj];
                    acc[oo][0] += w * fr[0+ki][0+kj];
                    acc[oo][1] += w * fr[0+ki][1+kj];
                    acc[oo][2] += w * fr[1+ki][0+kj];
                    acc[oo][3] += w * fr[1+ki][1+kj];
                }
        }
    }
    #pragma unroll
    for (int oo = 0; oo < 8; oo++){
        int oc = gr*8 + oo;
        float* ob = out + ((size_t)b*C + oc)*HW;
        ob[(ti+pi0+0)*WD + (tj+pj0+0)] = acc[oo][0];
        ob[(ti+pi0+0)*WD + (tj+pj0+1)] = acc[oo][1];
        ob[(ti+pi0+1)*WD + (tj+pj0+0)] = acc[oo][2];
        ob[(ti+pi0+1)*WD + (tj+pj0+1)] = acc[oo][3];
    }
}

// ---------------- K6b: out += M[b] @ V (attention+proj epilogue) -------------
__global__ __launch_bounds__(256) void k6b_pv(const u16* __restrict__ qkv,
                                              const float* __restrict__ Mm,
                                              float* __restrict__ out){
    int b   = blockIdx.z;
    int co0 = blockIdx.y * 16;
    int px  = blockIdx.x * 1024 + threadIdx.x * 4;
    __shared__ float ms[16*96];
    for (int i = threadIdx.x; i < 16*96; i += 256)
        ms[i] = Mm[((size_t)b*C + co0)*C + i];
    __syncthreads();
    const u16* vb = qkv + ((size_t)b*C3 + 2*C)*HW + px;
    float* ob = out + ((size_t)b*C + co0)*HW + px;
    float acc[16][4];
    #pragma unroll
    for (int i = 0; i < 16; i++){
        float4 o4 = *(const float4*)(ob + (size_t)i*HW);
        acc[i][0]=o4.x; acc[i][1]=o4.y; acc[i][2]=o4.z; acc[i][3]=o4.w;
    }
    for (int c = 0; c < 96; c++){
        uint2 vv = *(const uint2*)(vb + (size_t)c*HW);
        float v0 = bf2f((u16)(vv.x & 0xffffu));
        float v1 = bf2f((u16)(vv.x >> 16));
        float v2 = bf2f((u16)(vv.y & 0xffffu));
        float v3 = bf2f((u16)(vv.y >> 16));
        #pragma unroll
        for (int i = 0; i < 16; i++){
            float w = ms[i*96 + c];
            acc[i][0] += w*v0; acc[i][1] += w*v1;
            acc[i][2] += w*v2; acc[i][3] += w*v3;
        }
    }
    #pragma unroll
    for (int i = 0; i < 16; i++)
        *(float4*)(ob + (size_t)i*HW) = make_float4(acc[i][0],acc[i][1],acc[i][2],acc[i][3]);
}

// -----------------------------------------------------------------------------
extern "C" void kernel_launch(void* const* d_in, const int* in_sizes, int n_in,
                              void* d_out, int out_size, void* d_ws, size_t ws_size,
                              hipStream_t stream){
    (void)in_sizes; (void)n_in; (void)out_size; (void)ws_size;
    const float* x           = (const float*)d_in[0];
    const float* spectral    = (const float*)d_in[1];
    const float* temperature = (const float*)d_in[2];
    const float* w_qkv       = (const float*)d_in[3];
    const float* w_dw        = (const float*)d_in[4];
    const float* w_proj      = (const float*)d_in[5];
    const float* w_fc        = (const float*)d_in[6];
    const float* b_fc        = (const float*)d_in[7];
    const float* w_dep       = (const float*)d_in[8];
    const float* b_dep       = (const float*)d_in[9];
    const float* w_se1       = (const float*)d_in[10];
    const float* b_se1       = (const float*)d_in[11];
    const float* w_se2       = (const float*)d_in[12];
    const float* b_se2       = (const float*)d_in[13];
    const float* w_saw1      = (const float*)d_in[14];
    const float* b_saw1      = (const float*)d_in[15];
    const float* w_saw2      = (const float*)d_in[16];
    const float* b_saw2      = (const float*)d_in[17];
    const float* w_sgp       = (const float*)d_in[18];
    const float* b_sgp       = (const float*)d_in[19];
    float* out = (float*)d_out;
    char* ws   = (char*)d_ws;

    // workspace layout (total ~112 MB)
    u16*   qkv  = (u16*)ws;                        // 4*288*25600 bf16 = 58,982,400 B
    float* Y    = (float*)(ws + 58982400ull);      // 288*25600 f32   = 29,491,200 B
    u16*   fws  = (u16*)(ws + 88473600ull);        // 4*25600*108 bf16= 22,118,400 B
    float* sm   = (float*)(ws + 110592000ull);     // small pool (fp32)
    float* xsum  = sm;            // 384
    float* swg   = sm + 384;      // 384
    float* esgg  = sm + 768;      // 384
    float* weff  = sm + 1152;     // 110,592
    float* Mm    = sm + 111744;   // 36,864
    float* gpart = sm + 148608;   // 134,400   -> end 283,008 floats

    k0_xsum <<<dim3(NB*C),     dim3(256), 0, stream>>>(x, xsum);
    k1_small<<<dim3(1),        dim3(256), 0, stream>>>(spectral, xsum,
                w_se1, b_se1, w_se2, b_se2, w_saw1, b_saw1, w_saw2, b_saw2,
                w_sgp, b_sgp, w_qkv, swg, esgg, weff);
    for (int b = 0; b < NB; b++){
        k2a_qkv <<<dim3(25,18), dim3(256), 0, stream>>>(x, weff, Y, b);
        k2b_dw  <<<dim3(20,C3), dim3(256), 0, stream>>>(Y, w_dw, qkv, b);
    }
    k3_fc   <<<dim3(400,NB),   dim3(256), 0, stream>>>(qkv, w_fc, b_fc, fws);
    k4_gram <<<dim3(25,NH,NB), dim3(256), 0, stream>>>(qkv, gpart);
    k5_attn <<<dim3(NB),       dim3(256), 0, stream>>>(gpart, esgg, temperature, w_proj, Mm);
    k6a_dep <<<dim3(20,20,NB), dim3(192), 0, stream>>>(fws, w_dep, b_dep, out);
    k6b_pv  <<<dim3(25,6,NB),  dim3(256), 0, stream>>>(qkv, Mm, out);
}